// Round 10
// baseline (361.056 us; speedup 1.0000x reference)
//
#include <hip/hip_runtime.h>
#include <math.h>

#define B 2
#define N 8192
#define M 8192
#define D 64
#define KNN 16
#define BM (B * M)           // 16384
#define GC 16                // grid cells per axis
#define NC (GC * GC * GC)    // 4096
#define NSC 64               // supercells (4x4x4)
#define WTMAX 192            // max wave-table entries per batch (proven bound)
#define NSL 8                // candidate slices (waves) per query group
#define CAP 20               // per-lane LDS candidate buffer slots
#define TCAP 448             // per-wave LDS point-tile capacity

// Per-query filter radius: lambda~60 expected in-(clipped-)ball candidates.
// nc = #axes within 0.16 of a domain wall (density octant compensation).
// MUST be recomputed identically in k_knn and k_tail.
__device__ __forceinline__ float query_cutr(float qx, float qy, float qz) {
    int nc = ((qx < 0.16f) | (qx > 0.84f)) + ((qy < 0.16f) | (qy > 0.84f))
           + ((qz < 0.16f) | (qz > 0.84f));
    return nc == 0 ? 0.121f : nc == 1 ? 0.1525f : nc == 2 ? 0.1921f : 0.242f;
}

// Sorted-insert of (dd,ii) into a per-lane top-16 (ascending). Strict < keeps
// earlier-inserted on exact ties.
#define CHAIN_INS(VARR, IARR, DVAL, IVAL) do {                          \
    float _dd = (DVAL); int _ii = (IVAL);                               \
    _Pragma("unroll")                                                   \
    for (int _r = 0; _r < KNN; ++_r) {                                  \
        bool  _sm = _dd < VARR[_r];                                     \
        float _tv = VARR[_r]; int _ti = IARR[_r];                       \
        VARR[_r] = _sm ? _dd : _tv;  IARR[_r] = _sm ? _ii : _ti;        \
        _dd      = _sm ? _tv : _dd;  _ii      = _sm ? _ti : _ii;        \
    }                                                                   \
} while (0)
#define CHAIN_INSERT(DVAL, IVAL) CHAIN_INS(v, id, DVAL, IVAL)

// Scan the wave's tile (broadcast ds_read_b128), buffer passing tile slots,
// drain (recompute d^2 from tile, idx from .w), reset.
#define KFLUSH() do {                                                   \
    for (int _t = 0; _t < cur; ++_t) {                                  \
        float4 _p = tile[wv][_t];              /* bcast, conflict-free */\
        float _dx = _p.x - qx, _dy = _p.y - qy, _dz = _p.z - qz;        \
        float _dv = fmaf(_dx, _dx, fmaf(_dy, _dy, _dz * _dz));          \
        if (_dv < fcut) {                                               \
            if (cnt < CAP) {                                            \
                ibuf[cnt][tid] = (unsigned short)_t;                    \
                ++cnt;                                                  \
            } else {                           /* overflow (rare) */    \
                CHAIN_INSERT(_dv, __float_as_int(_p.w));                \
            }                                                           \
        }                                                               \
    }                                                                   \
    int _mx = cnt;                                                      \
    _Pragma("unroll")                                                   \
    for (int _o = 32; _o; _o >>= 1)                                     \
        _mx = max(_mx, __shfl_xor(_mx, _o, 64));                        \
    _mx = __builtin_amdgcn_readfirstlane(_mx);                          \
    for (int _t2 = 0; _t2 < _mx; ++_t2) {                               \
        int _tp = (_t2 < cnt) ? (int)ibuf[_t2][tid] : 0;                \
        float4 _p = tile[wv][_tp];             /* per-lane LDS gather */\
        float _dx = _p.x - qx, _dy = _p.y - qy, _dz = _p.z - qz;        \
        float _dv = fmaf(_dx, _dx, fmaf(_dy, _dy, _dz * _dz));          \
        if (_t2 < cnt && _dv < v[KNN - 1])                              \
            CHAIN_INSERT(_dv, __float_as_int(_p.w));                    \
    }                                                                   \
    cnt = 0; cur = 0;                                                   \
} while (0)

// ---------------------------------------------------------------------------
// Kernel: FUSED histogram (blocks 0..63) + f = feature1 @ Wp + bp (all 512).
// Proj: wave per 8 rows, lane = output channel, shfl row-broadcast.
__global__ __launch_bounds__(256) void k_prep(const float* __restrict__ feat,
                                              const float* __restrict__ Wp,
                                              const float* __restrict__ bp,
                                              const float* __restrict__ xyz1,
                                              const float* __restrict__ xyz2,
                                              unsigned* __restrict__ pcount,
                                              unsigned* __restrict__ qcount,
                                              float* __restrict__ f) {
    if (blockIdx.x < 64) {                    // histogram part (16384 threads)
        int i = blockIdx.x * 256 + threadIdx.x;
        int b = i >> 13;
        const float* p = xyz1 + (size_t)i * 3;
        int cx = max(0, min(GC - 1, (int)(p[0] * GC)));
        int cy = max(0, min(GC - 1, (int)(p[1] * GC)));
        int cz = max(0, min(GC - 1, (int)(p[2] * GC)));
        atomicAdd(&pcount[b * NC + (cz * GC + cy) * GC + cx], 1u);
        const float* q = xyz2 + (size_t)i * 3;
        int qx = max(0, min(GC - 1, (int)(q[0] * GC)));
        int qy = max(0, min(GC - 1, (int)(q[1] * GC)));
        int qz = max(0, min(GC - 1, (int)(q[2] * GC)));
        int sc = ((qz >> 2) * 4 + (qy >> 2)) * 4 + (qx >> 2);
        atomicAdd(&qcount[b * NSC + sc], 1u);
    }
    // projection part
    int c  = threadIdx.x & 63;
    int wv = threadIdx.x >> 6;
    int row0 = blockIdx.x * 32 + wv * 8;
    float wp[64];
#pragma unroll
    for (int d = 0; d < 64; ++d) wp[d] = Wp[d * 64 + c];   // coalesced, L1-hot
    float bpc = bp[c];
    float fv[8], acc[8];
#pragma unroll
    for (int r = 0; r < 8; ++r) {
        fv[r]  = feat[(size_t)(row0 + r) * 64 + c];        // coalesced
        acc[r] = bpc;
    }
#pragma unroll
    for (int d = 0; d < 64; ++d) {
#pragma unroll
        for (int r = 0; r < 8; ++r)
            acc[r] = fmaf(__shfl(fv[r], d, 64), wp[d], acc[r]);
    }
#pragma unroll
    for (int r = 0; r < 8; ++r)
        f[(size_t)(row0 + r) * 64 + c] = acc[r];
}

// Kernel: blocks 0,1 = 4096-bin exclusive scan (points, per batch);
//         blocks 2,3 = 64-bin query scan + wave-table build (shfl scans).
// wtab entry packs (qoff<<7) | qnum.
__global__ __launch_bounds__(256) void k_scan(const unsigned* __restrict__ pcount,
                                              const unsigned* __restrict__ qcount,
                                              unsigned* __restrict__ pstart,
                                              unsigned* __restrict__ pcur,
                                              unsigned* __restrict__ qcur,
                                              int* __restrict__ wtab,
                                              int* __restrict__ ntab) {
    __shared__ unsigned wsum[4];
    int blk = blockIdx.x;
    if (blk < 2) {
        int b = blk;
        int t = threadIdx.x;
        int base = b * NC + t * 16;
        unsigned c[16]; unsigned tsum = 0;
#pragma unroll
        for (int k = 0; k < 16; ++k) { c[k] = pcount[base + k]; tsum += c[k]; }
        int lane = t & 63, wv = t >> 6;
        unsigned x = tsum;
#pragma unroll
        for (int off = 1; off < 64; off <<= 1) {
            unsigned y = __shfl_up(x, off, 64);
            if (lane >= off) x += y;
        }
        if (lane == 63) wsum[wv] = x;
        __syncthreads();
        unsigned pre = 0;
        for (int k2 = 0; k2 < wv; ++k2) pre += wsum[k2];
        unsigned run = pre + x - tsum;
#pragma unroll
        for (int k = 0; k < 16; ++k) {
            pstart[base + k] = run; pcur[base + k] = run; run += c[k];
        }
    } else {
        int b = blk - 2;
        if (threadIdx.x >= 64) return;
        int lane = threadIdx.x;
        int c = (int)qcount[b * NSC + lane];
        int x = c;
#pragma unroll
        for (int off = 1; off < 64; off <<= 1) {
            int y = __shfl_up(x, off, 64);
            if (lane >= off) x += y;
        }
        int run = x - c;                         // exclusive prefix of queries
        qcur[b * NSC + lane] = (unsigned)run;
        int ne = (c + 63) >> 6;                  // entries for this supercell
        int e = ne;
#pragma unroll
        for (int off = 1; off < 64; off <<= 1) {
            int y = __shfl_up(e, off, 64);
            if (lane >= off) e += y;
        }
        int eoff = e - ne;                       // exclusive prefix of entries
        for (int j = 0; j < ne; ++j)
            wtab[b * WTMAX + eoff + j] = ((run + j * 64) << 7) | min(64, c - j * 64);
        if (lane == 63) ntab[b] = eoff + ne;
    }
}

// Kernel: scatter points (cell-sorted, |p|^2 in .w) and queries (supercell-sorted).
__global__ __launch_bounds__(256) void k_scatter(const float* __restrict__ xyz1,
                                                 const float* __restrict__ xyz2,
                                                 unsigned* __restrict__ pcur,
                                                 unsigned* __restrict__ qcur,
                                                 float4* __restrict__ spts,
                                                 int* __restrict__ sidx,
                                                 float4* __restrict__ squery) {
    int i = blockIdx.x * 256 + threadIdx.x;   // < B*N
    int b = i >> 13;
    const float* p = xyz1 + (size_t)i * 3;
    float x = p[0], y = p[1], z = p[2];
    int cx = max(0, min(GC - 1, (int)(x * GC)));
    int cy = max(0, min(GC - 1, (int)(y * GC)));
    int cz = max(0, min(GC - 1, (int)(z * GC)));
    unsigned pos = atomicAdd(&pcur[b * NC + (cz * GC + cy) * GC + cx], 1u);
    spts[(size_t)b * N + pos] = make_float4(x, y, z, fmaf(x, x, fmaf(y, y, z * z)));
    sidx[(size_t)b * N + pos] = i & (N - 1);

    const float* q = xyz2 + (size_t)i * 3;
    float qx = q[0], qy = q[1], qz = q[2];
    int ax = max(0, min(GC - 1, (int)(qx * GC)));
    int ay = max(0, min(GC - 1, (int)(qy * GC)));
    int az = max(0, min(GC - 1, (int)(qz * GC)));
    int sc = ((az >> 2) * 4 + (ay >> 2)) * 4 + (ax >> 2);
    unsigned qpos = atomicAdd(&qcur[b * NSC + sc], 1u);
    squery[(size_t)b * M + qpos] = make_float4(qx, qy, qz, __int_as_float(i));
}

// Kernel: grid KNN partials, slice-parallel (unchanged structure from R9).
__global__ __launch_bounds__(256) void k_knn(const float4* __restrict__ spts,
                                             const float4* __restrict__ squery,
                                             const unsigned* __restrict__ pstart,
                                             const unsigned* __restrict__ pcount,
                                             const int* __restrict__ wtab,
                                             const int* __restrict__ ntab,
                                             float* __restrict__ part_d,
                                             int* __restrict__ part_i) {
    __shared__ float4         tile[4][TCAP];    // 28 KB, per-wave (idx in .w)
    __shared__ unsigned short ibuf[CAP][256];   // 10 KB, [slot][tid]
    int bid = blockIdx.x;
    int b   = bid / (WTMAX * 2);
    int rem = bid - b * (WTMAX * 2);
    int ti  = rem >> 1;
    int sq  = rem & 1;
    if (ti >= ntab[b]) return;
    int e = wtab[b * WTMAX + ti];
    int qnum = e & 127, qoff = (e >> 7) & 0x3FFF;
    int tid = threadIdx.x;
    int lane = tid & 63;
    int wv = tid >> 6;
    int s = sq * 4 + wv;                        // slice 0..7

    int sl = lane < qnum ? lane : qnum - 1;     // surplus lanes dup last query
    float4 q4 = squery[(size_t)b * M + qoff + sl];
    float qx = q4.x, qy = q4.y, qz = q4.z;
    float cutr = query_cutr(qx, qy, qz);
    float fcut = cutr * cutr;                   // filter in true d^2 space

    int lx0 = max(0, (int)floorf((qx - cutr) * GC));
    int lx1 = min(GC - 1, (int)floorf((qx + cutr) * GC));
    int ly0 = max(0, (int)floorf((qy - cutr) * GC));
    int ly1 = min(GC - 1, (int)floorf((qy + cutr) * GC));
    int lz0 = max(0, (int)floorf((qz - cutr) * GC));
    int lz1 = min(GC - 1, (int)floorf((qz + cutr) * GC));
#pragma unroll
    for (int off = 1; off < 64; off <<= 1) {
        lx0 = min(lx0, __shfl_xor(lx0, off, 64));
        lx1 = max(lx1, __shfl_xor(lx1, off, 64));
        ly0 = min(ly0, __shfl_xor(ly0, off, 64));
        ly1 = max(ly1, __shfl_xor(ly1, off, 64));
        lz0 = min(lz0, __shfl_xor(lz0, off, 64));
        lz1 = max(lz1, __shfl_xor(lz1, off, 64));
    }
    int bx0 = __builtin_amdgcn_readfirstlane(lx0);
    int bx1 = __builtin_amdgcn_readfirstlane(lx1);
    int by0 = __builtin_amdgcn_readfirstlane(ly0);
    int by1 = __builtin_amdgcn_readfirstlane(ly1);
    int bz0 = __builtin_amdgcn_readfirstlane(lz0);
    int bz1 = __builtin_amdgcn_readfirstlane(lz1);

    float v[KNN]; int id[KNN];
#pragma unroll
    for (int r = 0; r < KNN; ++r) { v[r] = 3.4e38f; id[r] = 0; }
    int cnt = 0, cur = 0;
    int pb = b * N, cb = b * NC;
    int xspan = bx1 - bx0;

    int rix = 0;
    for (int zz = bz0; zz <= bz1; ++zz)
        for (int yy = by0; yy <= by1; ++yy, ++rix) {
            if ((rix & 7) != s) continue;       // this wave's rows only
            int codeL = cb + (zz * GC + yy) * GC + bx0;   // uniform
            int st = (int)pstart[codeL];
            int en = (int)pstart[codeL + xspan] + (int)pcount[codeL + xspan];
            st = __builtin_amdgcn_readfirstlane(st);
            en = __builtin_amdgcn_readfirstlane(en);
            int len = en - st;
            if (cur + len > TCAP) KFLUSH();
            for (int u = lane; u < len; u += 64) {        // vector loads
                float4 p = spts[pb + st + u];
                p.w = __int_as_float(st + u);             // pack sorted idx
                tile[wv][cur + u] = p;
            }
            cur += len;
        }
    KFLUSH();

    if (lane < qnum) {
        int col = b * M + qoff + lane;          // sorted-query column
#pragma unroll
        for (int r = 0; r < KNN; ++r) {
            part_d[(size_t)(s * KNN + r) * BM + col] = v[r];
            part_i[(size_t)(s * KNN + r) * BM + col] = id[r];
        }
    }
}

// Kernel: FUSED merge + inline fixup + MLP/reduce. Block owns 64 sorted queries.
// Phase A (tid=[sub][ql]): 2-stage merge of 8x16 partials -> final idx to LDS,
//   weight to global; missed lanes (d16 >= cutr^2) fixed inline by the sub-0
//   wave (brute force over N + bitonic tournament). Misses ~0 expected.
// Phase B (tid=[wave][c]): each wave runs the MLP for 16 of the block's
//   queries: W2 column in VGPRs, h transposed through a private LDS region
//   (aliases sd), broadcast ds_read_b128 for the 64x16 y-accumulation.
__global__ __launch_bounds__(256) void k_tail(const float4* __restrict__ squery,
                                              const float* __restrict__ part_d,
                                              const int* __restrict__ part_i,
                                              const int* __restrict__ sidx,
                                              const float4* __restrict__ spts,
                                              const float* __restrict__ xyz1,
                                              const float* __restrict__ f,
                                              const float* __restrict__ W1,
                                              const float* __restrict__ b1,
                                              const float* __restrict__ W2,
                                              const float* __restrict__ b2,
                                              float* __restrict__ out,
                                              float* __restrict__ w_out) {
    __shared__ __align__(16) float sd[4][KNN][64];   // 16 KB (phase B: hT alias)
    __shared__ int   si[4][KNN][64];                 // 16 KB
    __shared__ int   fidx[64][KNN];                  //  4 KB
    int tid = threadIdx.x;
    int ql  = tid & 63;
    int sub = tid >> 6;
    int sqid = blockIdx.x * 64 + ql;    // 0..BM-1
    int b = sqid >> 13;

    { // ---- Phase A: merge ----
        float v[KNN]; int id[KNN];
#pragma unroll
        for (int r = 0; r < KNN; ++r) { v[r] = 3.4e38f; id[r] = 0; }
#pragma unroll 4
        for (int e = sub * 32; e < sub * 32 + 32; ++e) {
            float dv = part_d[(size_t)e * BM + sqid];      // coalesced
            if (dv < v[KNN - 1]) {
                int ii = part_i[(size_t)e * BM + sqid];
                CHAIN_INSERT(dv, ii);
            }
        }
#pragma unroll
        for (int r = 0; r < KNN; ++r) { sd[sub][r][ql] = v[r]; si[sub][r][ql] = id[r]; }
        __syncthreads();

        if (sub == 0) {
            for (int e = KNN; e < 4 * KNN; ++e) {
                float dv = sd[e >> 4][e & 15][ql];
                if (dv < v[KNN - 1]) CHAIN_INSERT(dv, si[e >> 4][e & 15][ql]);
            }
            float4 q4 = squery[sqid];
            float cutr = query_cutr(q4.x, q4.y, q4.z);
            bool miss = !(v[KNN - 1] < cutr * cutr * 0.9999f);
            unsigned long long mmask = __ballot(miss);
            while (mmask) {                    // inline fixup (normally skipped)
                int ml = __ffsll(mmask) - 1;
                mmask &= mmask - 1;
                int msq = blockIdx.x * 64 + ml;
                int mb = msq >> 13;
                float4 mq = squery[msq];
                float fv2[KNN]; int fi2[KNN];
#pragma unroll
                for (int r = 0; r < KNN; ++r) { fv2[r] = 3.4e38f; fi2[r] = 0; }
                for (int t = ql; t < N; t += 64) {
                    float4 p = spts[(size_t)mb * N + t];
                    float dx = p.x - mq.x, dy = p.y - mq.y, dz = p.z - mq.z;
                    float dv = fmaf(dx, dx, fmaf(dy, dy, dz * dz));
                    if (dv < fv2[KNN - 1]) CHAIN_INS(fv2, fi2, dv, t);
                }
#pragma unroll
                for (int rd = 0; rd < 6; ++rd) {   // bitonic tournament
                    int dl = 1 << rd;
                    float nv[KNN]; int nid[KNN];
#pragma unroll
                    for (int i2 = 0; i2 < KNN; ++i2) {
                        float pv = __shfl_xor(fv2[KNN - 1 - i2], dl, 64);
                        int   pi = __shfl_xor(fi2[KNN - 1 - i2], dl, 64);
                        bool take = fv2[i2] <= pv;
                        nv[i2]  = take ? fv2[i2] : pv;
                        nid[i2] = take ? fi2[i2] : pi;
                    }
#pragma unroll
                    for (int st = 8; st; st >>= 1) {
#pragma unroll
                        for (int i2 = 0; i2 < KNN; ++i2) {
                            if (!(i2 & st)) {
                                int j2 = i2 | st;
                                bool sw = nv[i2] > nv[j2];
                                float ta = sw ? nv[j2] : nv[i2];
                                float tb = sw ? nv[i2] : nv[j2];
                                int ia = sw ? nid[j2] : nid[i2];
                                int ib = sw ? nid[i2] : nid[j2];
                                nv[i2] = ta; nv[j2] = tb; nid[i2] = ia; nid[j2] = ib;
                            }
                        }
                    }
#pragma unroll
                    for (int i2 = 0; i2 < KNN; ++i2) { fv2[i2] = nv[i2]; fi2[i2] = nid[i2]; }
                }
                if (ql == ml) {
#pragma unroll
                    for (int r = 0; r < KNN; ++r) { v[r] = fv2[r]; id[r] = fi2[r]; }
                }
            }
            int gq = __float_as_int(q4.w);
            w_out[gq] = (v[0] > 0.03f) ? 10.0f : 1.0f;
#pragma unroll
            for (int r = 0; r < KNN; ++r)
                fidx[ql][r] = sidx[b * N + id[r]];        // original indices
        }
    }
    __syncthreads();

    // ---- Phase B: MLP + reduce (lane = channel c; wave wv -> 16 queries) ----
    int c  = tid & 63;
    int wv = tid >> 6;
    float* hT = &sd[0][0][0];            // alias: per-wave 1024-float region
    float w2c[64];
#pragma unroll
    for (int d = 0; d < 64; ++d) w2c[d] = W2[d * 64 + c];  // coalesced, L1-hot
    float w10 = W1[c], w11 = W1[64 + c], w12 = W1[128 + c];
    float b1c = b1[c], b2c = b2[c];

    for (int j = 0; j < 16; ++j) {
        int mq  = blockIdx.x * 64 + wv * 16 + j;   // sorted query id
        int bb  = mq >> 13;
        float4 q4 = squery[mq];                    // wave-uniform s_load
        float qx = q4.x, qy = q4.y, qz = q4.z;
        int gq = __float_as_int(q4.w);

        int nidx[KNN];
#pragma unroll
        for (int k = 0; k < KNN; ++k)
            nidx[k] = fidx[wv * 16 + j][k];        // broadcast ds_read

        float h[KNN];
#pragma unroll
        for (int k = 0; k < KNN; ++k) {
            const float* p = xyz1 + ((size_t)bb * N + nidx[k]) * 3;
            float gx = p[0] - qx, gy = p[1] - qy, gz = p[2] - qz;
            float t = fmaf(gx, w10, b1c);
            t = fmaf(gy, w11, t);
            t = fmaf(gz, w12, t);
            h[k] = fmaxf(t, 0.f);
        }
#pragma unroll
        for (int k = 0; k < KNN; k += 4)
            *(float4*)&hT[wv * 1024 + c * 16 + k] =
                make_float4(h[k], h[k+1], h[k+2], h[k+3]);
        // same-wave LDS RAW: compiler inserts lgkmcnt wait; no barrier needed.
        float y[KNN];
#pragma unroll
        for (int k = 0; k < KNN; ++k) y[k] = 0.f;
#pragma unroll 4
        for (int d = 0; d < 64; ++d) {
            const float4* hp = (const float4*)&hT[wv * 1024 + d * 16]; // bcast
            float hh[16];
            *(float4*)&hh[0]  = hp[0];
            *(float4*)&hh[4]  = hp[1];
            *(float4*)&hh[8]  = hp[2];
            *(float4*)&hh[12] = hp[3];
#pragma unroll
            for (int k = 0; k < KNN; ++k)
                y[k] = fmaf(hh[k], w2c[d], y[k]);
        }
        float acc = 0.f;
#pragma unroll
        for (int k = 0; k < KNN; ++k) {
            float gfv = f[((size_t)bb * N + nidx[k]) * 64 + c];  // coalesced
            acc = fmaf(y[k] + b2c, gfv, acc);
        }
        out[(size_t)gq * 64 + c] = acc * 0.25f;    // 1/sqrt(16)
    }
}

extern "C" void kernel_launch(void* const* d_in, const int* in_sizes, int n_in,
                              void* d_out, int out_size, void* d_ws, size_t ws_size,
                              hipStream_t stream) {
    const float* feature1 = (const float*)d_in[0];
    const float* xyz1     = (const float*)d_in[1];
    const float* xyz2     = (const float*)d_in[2];
    const float* Wp       = (const float*)d_in[3];
    const float* bp       = (const float*)d_in[4];
    const float* W1       = (const float*)d_in[5];
    const float* b1       = (const float*)d_in[6];
    const float* W2       = (const float*)d_in[7];
    const float* b2       = (const float*)d_in[8];
    float* out = (float*)d_out;

    char* w = (char*)d_ws;
    float4*   spts   = (float4*)w;    w += (size_t)B * N * 16;
    float4*   squery = (float4*)w;    w += (size_t)B * M * 16;
    float*    f      = (float*)w;     w += (size_t)B * N * D * 4;
    int*      sidx   = (int*)w;       w += (size_t)B * N * 4;
    unsigned* pcount = (unsigned*)w;  w += (size_t)B * NC * 4;
    unsigned* qcount = (unsigned*)w;  w += (size_t)B * NSC * 4;
    unsigned* pstart = (unsigned*)w;  w += (size_t)B * NC * 4;
    unsigned* pcur   = (unsigned*)w;  w += (size_t)B * NC * 4;
    unsigned* qcur   = (unsigned*)w;  w += (size_t)B * NSC * 4;
    int*      wtab   = (int*)w;       w += (size_t)B * WTMAX * 4;
    int*      ntab   = (int*)w;       w += 16;
    float*    partd  = (float*)w;     w += (size_t)NSL * KNN * BM * 4;
    int*      parti  = (int*)w;       w += (size_t)NSL * KNN * BM * 4;
    float*    w_out  = out + (size_t)BM * D;

    // zero pcount + qcount (contiguous)
    hipMemsetAsync(pcount, 0, (size_t)(B * NC + B * NSC) * 4, stream);

    k_prep<<<B * N / 32, 256, 0, stream>>>(feature1, Wp, bp, xyz1, xyz2,
                                           pcount, qcount, f);
    k_scan<<<4, 256, 0, stream>>>(pcount, qcount, pstart, pcur, qcur, wtab, ntab);
    k_scatter<<<BM / 256, 256, 0, stream>>>(xyz1, xyz2, pcur, qcur, spts, sidx, squery);
    k_knn<<<B * WTMAX * 2, 256, 0, stream>>>(spts, squery, pstart, pcount,
                                             wtab, ntab, partd, parti);
    k_tail<<<BM / 64, 256, 0, stream>>>(squery, partd, parti, sidx, spts, xyz1,
                                        f, W1, b1, W2, b2, out, w_out);
}

// Round 11
// 254.739 us; speedup vs baseline: 1.4174x; 1.4174x over previous
//
#include <hip/hip_runtime.h>
#include <math.h>

#define B 2
#define N 8192
#define M 8192
#define D 64
#define KNN 16
#define BM (B * M)           // 16384
#define GC 16                // grid cells per axis
#define NC (GC * GC * GC)    // 4096
#define NSC 64               // supercells (4x4x4)
#define WTMAX 192            // max wave-table entries per batch (proven bound)
#define NSL 8                // candidate slices (waves) per query group
#define CAP 20               // per-lane LDS candidate buffer slots
#define TCAP 448             // per-wave LDS point-tile capacity

using frag_ab = __attribute__((ext_vector_type(8))) short;   // 8 bf16 (4 VGPRs)
using frag_cd = __attribute__((ext_vector_type(4))) float;   // 4 fp32

// fp32 -> bf16 (round-to-nearest-even), bits in a short.
__device__ __forceinline__ short f2bf(float x) {
    unsigned u = __float_as_uint(x);
    u += 0x7fffu + ((u >> 16) & 1u);
    return (short)(u >> 16);
}

// Per-query filter radius: lambda~60 expected in-(clipped-)ball candidates.
// nc = #axes within 0.16 of a domain wall (density octant compensation).
// MUST be recomputed identically in k_knn and k_merge.
__device__ __forceinline__ float query_cutr(float qx, float qy, float qz) {
    int nc = ((qx < 0.16f) | (qx > 0.84f)) + ((qy < 0.16f) | (qy > 0.84f))
           + ((qz < 0.16f) | (qz > 0.84f));
    return nc == 0 ? 0.121f : nc == 1 ? 0.1525f : nc == 2 ? 0.1921f : 0.242f;
}

// Sorted-insert of (dd,ii) into a per-lane top-16 (ascending). Strict < keeps
// earlier-inserted on exact ties.
#define CHAIN_INS(VARR, IARR, DVAL, IVAL) do {                          \
    float _dd = (DVAL); int _ii = (IVAL);                               \
    _Pragma("unroll")                                                   \
    for (int _r = 0; _r < KNN; ++_r) {                                  \
        bool  _sm = _dd < VARR[_r];                                     \
        float _tv = VARR[_r]; int _ti = IARR[_r];                       \
        VARR[_r] = _sm ? _dd : _tv;  IARR[_r] = _sm ? _ii : _ti;        \
        _dd      = _sm ? _tv : _dd;  _ii      = _sm ? _ti : _ii;        \
    }                                                                   \
} while (0)
#define CHAIN_INSERT(DVAL, IVAL) CHAIN_INS(v, id, DVAL, IVAL)

// Scan the wave's tile (broadcast ds_read_b128), buffer passing tile slots,
// drain (recompute d^2 from tile, idx from .w), reset.
#define KFLUSH() do {                                                   \
    for (int _t = 0; _t < cur; ++_t) {                                  \
        float4 _p = tile[wv][_t];              /* bcast, conflict-free */\
        float _dx = _p.x - qx, _dy = _p.y - qy, _dz = _p.z - qz;        \
        float _dv = fmaf(_dx, _dx, fmaf(_dy, _dy, _dz * _dz));          \
        if (_dv < fcut) {                                               \
            if (cnt < CAP) {                                            \
                ibuf[cnt][tid] = (unsigned short)_t;                    \
                ++cnt;                                                  \
            } else {                           /* overflow (rare) */    \
                CHAIN_INSERT(_dv, __float_as_int(_p.w));                \
            }                                                           \
        }                                                               \
    }                                                                   \
    int _mx = cnt;                                                      \
    _Pragma("unroll")                                                   \
    for (int _o = 32; _o; _o >>= 1)                                     \
        _mx = max(_mx, __shfl_xor(_mx, _o, 64));                        \
    _mx = __builtin_amdgcn_readfirstlane(_mx);                          \
    for (int _t2 = 0; _t2 < _mx; ++_t2) {                               \
        int _tp = (_t2 < cnt) ? (int)ibuf[_t2][tid] : 0;                \
        float4 _p = tile[wv][_tp];             /* per-lane LDS gather */\
        float _dx = _p.x - qx, _dy = _p.y - qy, _dz = _p.z - qz;        \
        float _dv = fmaf(_dx, _dx, fmaf(_dy, _dy, _dz * _dz));          \
        if (_t2 < cnt && _dv < v[KNN - 1])                              \
            CHAIN_INSERT(_dv, __float_as_int(_p.w));                    \
    }                                                                   \
    cnt = 0; cur = 0;                                                   \
} while (0)

// ---------------------------------------------------------------------------
// Kernel: FUSED histogram (blocks 0..63) + f = feature1 @ Wp + bp (all 512).
__global__ __launch_bounds__(256) void k_prep(const float* __restrict__ feat,
                                              const float* __restrict__ Wp,
                                              const float* __restrict__ bp,
                                              const float* __restrict__ xyz1,
                                              const float* __restrict__ xyz2,
                                              unsigned* __restrict__ pcount,
                                              unsigned* __restrict__ qcount,
                                              float* __restrict__ f) {
    if (blockIdx.x < 64) {                    // histogram part (16384 threads)
        int i = blockIdx.x * 256 + threadIdx.x;
        int b = i >> 13;
        const float* p = xyz1 + (size_t)i * 3;
        int cx = max(0, min(GC - 1, (int)(p[0] * GC)));
        int cy = max(0, min(GC - 1, (int)(p[1] * GC)));
        int cz = max(0, min(GC - 1, (int)(p[2] * GC)));
        atomicAdd(&pcount[b * NC + (cz * GC + cy) * GC + cx], 1u);
        const float* q = xyz2 + (size_t)i * 3;
        int qx = max(0, min(GC - 1, (int)(q[0] * GC)));
        int qy = max(0, min(GC - 1, (int)(q[1] * GC)));
        int qz = max(0, min(GC - 1, (int)(q[2] * GC)));
        int sc = ((qz >> 2) * 4 + (qy >> 2)) * 4 + (qx >> 2);
        atomicAdd(&qcount[b * NSC + sc], 1u);
    }
    // projection part
    int c  = threadIdx.x & 63;
    int wv = threadIdx.x >> 6;
    int row0 = blockIdx.x * 32 + wv * 8;
    float wp[64];
#pragma unroll
    for (int d = 0; d < 64; ++d) wp[d] = Wp[d * 64 + c];   // coalesced, L1-hot
    float bpc = bp[c];
    float fv[8], acc[8];
#pragma unroll
    for (int r = 0; r < 8; ++r) {
        fv[r]  = feat[(size_t)(row0 + r) * 64 + c];        // coalesced
        acc[r] = bpc;
    }
#pragma unroll
    for (int d = 0; d < 64; ++d) {
#pragma unroll
        for (int r = 0; r < 8; ++r)
            acc[r] = fmaf(__shfl(fv[r], d, 64), wp[d], acc[r]);
    }
#pragma unroll
    for (int r = 0; r < 8; ++r)
        f[(size_t)(row0 + r) * 64 + c] = acc[r];
}

// Kernel: blocks 0,1 = 4096-bin exclusive scan (points, per batch);
//         blocks 2,3 = 64-bin query scan + wave-table build (shfl scans).
// wtab entry packs (qoff<<7) | qnum.
__global__ __launch_bounds__(256) void k_scan(const unsigned* __restrict__ pcount,
                                              const unsigned* __restrict__ qcount,
                                              unsigned* __restrict__ pstart,
                                              unsigned* __restrict__ pcur,
                                              unsigned* __restrict__ qcur,
                                              int* __restrict__ wtab,
                                              int* __restrict__ ntab) {
    __shared__ unsigned wsum[4];
    int blk = blockIdx.x;
    if (blk < 2) {
        int b = blk;
        int t = threadIdx.x;
        int base = b * NC + t * 16;
        unsigned c[16]; unsigned tsum = 0;
#pragma unroll
        for (int k = 0; k < 16; ++k) { c[k] = pcount[base + k]; tsum += c[k]; }
        int lane = t & 63, wv = t >> 6;
        unsigned x = tsum;
#pragma unroll
        for (int off = 1; off < 64; off <<= 1) {
            unsigned y = __shfl_up(x, off, 64);
            if (lane >= off) x += y;
        }
        if (lane == 63) wsum[wv] = x;
        __syncthreads();
        unsigned pre = 0;
        for (int k2 = 0; k2 < wv; ++k2) pre += wsum[k2];
        unsigned run = pre + x - tsum;
#pragma unroll
        for (int k = 0; k < 16; ++k) {
            pstart[base + k] = run; pcur[base + k] = run; run += c[k];
        }
    } else {
        int b = blk - 2;
        if (threadIdx.x >= 64) return;
        int lane = threadIdx.x;
        int c = (int)qcount[b * NSC + lane];
        int x = c;
#pragma unroll
        for (int off = 1; off < 64; off <<= 1) {
            int y = __shfl_up(x, off, 64);
            if (lane >= off) x += y;
        }
        int run = x - c;                         // exclusive prefix of queries
        qcur[b * NSC + lane] = (unsigned)run;
        int ne = (c + 63) >> 6;                  // entries for this supercell
        int e = ne;
#pragma unroll
        for (int off = 1; off < 64; off <<= 1) {
            int y = __shfl_up(e, off, 64);
            if (lane >= off) e += y;
        }
        int eoff = e - ne;                       // exclusive prefix of entries
        for (int j = 0; j < ne; ++j)
            wtab[b * WTMAX + eoff + j] = ((run + j * 64) << 7) | min(64, c - j * 64);
        if (lane == 63) ntab[b] = eoff + ne;
    }
}

// Kernel: scatter points (cell-sorted, |p|^2 in .w) and queries (supercell-sorted).
__global__ __launch_bounds__(256) void k_scatter(const float* __restrict__ xyz1,
                                                 const float* __restrict__ xyz2,
                                                 unsigned* __restrict__ pcur,
                                                 unsigned* __restrict__ qcur,
                                                 float4* __restrict__ spts,
                                                 int* __restrict__ sidx,
                                                 float4* __restrict__ squery) {
    int i = blockIdx.x * 256 + threadIdx.x;   // < B*N
    int b = i >> 13;
    const float* p = xyz1 + (size_t)i * 3;
    float x = p[0], y = p[1], z = p[2];
    int cx = max(0, min(GC - 1, (int)(x * GC)));
    int cy = max(0, min(GC - 1, (int)(y * GC)));
    int cz = max(0, min(GC - 1, (int)(z * GC)));
    unsigned pos = atomicAdd(&pcur[b * NC + (cz * GC + cy) * GC + cx], 1u);
    spts[(size_t)b * N + pos] = make_float4(x, y, z, fmaf(x, x, fmaf(y, y, z * z)));
    sidx[(size_t)b * N + pos] = i & (N - 1);

    const float* q = xyz2 + (size_t)i * 3;
    float qx = q[0], qy = q[1], qz = q[2];
    int ax = max(0, min(GC - 1, (int)(qx * GC)));
    int ay = max(0, min(GC - 1, (int)(qy * GC)));
    int az = max(0, min(GC - 1, (int)(qz * GC)));
    int sc = ((az >> 2) * 4 + (ay >> 2)) * 4 + (ax >> 2);
    unsigned qpos = atomicAdd(&qcur[b * NSC + sc], 1u);
    squery[(size_t)b * M + qpos] = make_float4(qx, qy, qz, __int_as_float(i));
}

// Kernel: grid KNN partials, slice-parallel (unchanged from R10).
__global__ __launch_bounds__(256) void k_knn(const float4* __restrict__ spts,
                                             const float4* __restrict__ squery,
                                             const unsigned* __restrict__ pstart,
                                             const unsigned* __restrict__ pcount,
                                             const int* __restrict__ wtab,
                                             const int* __restrict__ ntab,
                                             float* __restrict__ part_d,
                                             int* __restrict__ part_i) {
    __shared__ float4         tile[4][TCAP];    // 28 KB, per-wave (idx in .w)
    __shared__ unsigned short ibuf[CAP][256];   // 10 KB, [slot][tid]
    int bid = blockIdx.x;
    int b   = bid / (WTMAX * 2);
    int rem = bid - b * (WTMAX * 2);
    int ti  = rem >> 1;
    int sq  = rem & 1;
    if (ti >= ntab[b]) return;
    int e = wtab[b * WTMAX + ti];
    int qnum = e & 127, qoff = (e >> 7) & 0x3FFF;
    int tid = threadIdx.x;
    int lane = tid & 63;
    int wv = tid >> 6;
    int s = sq * 4 + wv;                        // slice 0..7

    int sl = lane < qnum ? lane : qnum - 1;     // surplus lanes dup last query
    float4 q4 = squery[(size_t)b * M + qoff + sl];
    float qx = q4.x, qy = q4.y, qz = q4.z;
    float cutr = query_cutr(qx, qy, qz);
    float fcut = cutr * cutr;                   // filter in true d^2 space

    int lx0 = max(0, (int)floorf((qx - cutr) * GC));
    int lx1 = min(GC - 1, (int)floorf((qx + cutr) * GC));
    int ly0 = max(0, (int)floorf((qy - cutr) * GC));
    int ly1 = min(GC - 1, (int)floorf((qy + cutr) * GC));
    int lz0 = max(0, (int)floorf((qz - cutr) * GC));
    int lz1 = min(GC - 1, (int)floorf((qz + cutr) * GC));
#pragma unroll
    for (int off = 1; off < 64; off <<= 1) {
        lx0 = min(lx0, __shfl_xor(lx0, off, 64));
        lx1 = max(lx1, __shfl_xor(lx1, off, 64));
        ly0 = min(ly0, __shfl_xor(ly0, off, 64));
        ly1 = max(ly1, __shfl_xor(ly1, off, 64));
        lz0 = min(lz0, __shfl_xor(lz0, off, 64));
        lz1 = max(lz1, __shfl_xor(lz1, off, 64));
    }
    int bx0 = __builtin_amdgcn_readfirstlane(lx0);
    int bx1 = __builtin_amdgcn_readfirstlane(lx1);
    int by0 = __builtin_amdgcn_readfirstlane(ly0);
    int by1 = __builtin_amdgcn_readfirstlane(ly1);
    int bz0 = __builtin_amdgcn_readfirstlane(lz0);
    int bz1 = __builtin_amdgcn_readfirstlane(lz1);

    float v[KNN]; int id[KNN];
#pragma unroll
    for (int r = 0; r < KNN; ++r) { v[r] = 3.4e38f; id[r] = 0; }
    int cnt = 0, cur = 0;
    int pb = b * N, cb = b * NC;
    int xspan = bx1 - bx0;

    int rix = 0;
    for (int zz = bz0; zz <= bz1; ++zz)
        for (int yy = by0; yy <= by1; ++yy, ++rix) {
            if ((rix & 7) != s) continue;       // this wave's rows only
            int codeL = cb + (zz * GC + yy) * GC + bx0;   // uniform
            int st = (int)pstart[codeL];
            int en = (int)pstart[codeL + xspan] + (int)pcount[codeL + xspan];
            st = __builtin_amdgcn_readfirstlane(st);
            en = __builtin_amdgcn_readfirstlane(en);
            int len = en - st;
            if (cur + len > TCAP) KFLUSH();
            for (int u = lane; u < len; u += 64) {        // vector loads
                float4 p = spts[pb + st + u];
                p.w = __int_as_float(st + u);             // pack sorted idx
                tile[wv][cur + u] = p;
            }
            cur += len;
        }
    KFLUSH();

    if (lane < qnum) {
        int col = b * M + qoff + lane;          // sorted-query column
#pragma unroll
        for (int r = 0; r < KNN; ++r) {
            part_d[(size_t)(s * KNN + r) * BM + col] = v[r];
            part_i[(size_t)(s * KNN + r) * BM + col] = id[r];
        }
    }
}

// Kernel: merge 8x16 partials per sorted query (2-stage, coalesced) + inline
// whole-wave fixup for missed queries. Writes w_out[gq] and idx_out in
// SORTED space (idx_out[r*BM + sqid], coalesced) holding ORIGINAL indices.
__global__ __launch_bounds__(256) void k_merge(const float4* __restrict__ squery,
                                               const float* __restrict__ part_d,
                                               const int* __restrict__ part_i,
                                               const int* __restrict__ sidx,
                                               const float4* __restrict__ spts,
                                               int* __restrict__ idx_out,
                                               float* __restrict__ w_out) {
    __shared__ float sd[4][KNN][64];    // 16 KB
    __shared__ int   si[4][KNN][64];    // 16 KB
    int tid = threadIdx.x;
    int ql  = tid & 63;
    int sub = tid >> 6;
    int sqid = blockIdx.x * 64 + ql;    // 0..BM-1
    int b = sqid >> 13;

    float v[KNN]; int id[KNN];
#pragma unroll
    for (int r = 0; r < KNN; ++r) { v[r] = 3.4e38f; id[r] = 0; }
#pragma unroll 4
    for (int e = sub * 32; e < sub * 32 + 32; ++e) {
        float dv = part_d[(size_t)e * BM + sqid];      // coalesced
        if (dv < v[KNN - 1]) {
            int ii = part_i[(size_t)e * BM + sqid];
            CHAIN_INSERT(dv, ii);
        }
    }
#pragma unroll
    for (int r = 0; r < KNN; ++r) { sd[sub][r][ql] = v[r]; si[sub][r][ql] = id[r]; }
    __syncthreads();
    if (sub != 0) return;

    for (int e = KNN; e < 4 * KNN; ++e) {
        float dv = sd[e >> 4][e & 15][ql];
        if (dv < v[KNN - 1]) CHAIN_INSERT(dv, si[e >> 4][e & 15][ql]);
    }
    float4 q4 = squery[sqid];
    float cutr = query_cutr(q4.x, q4.y, q4.z);
    bool miss = !(v[KNN - 1] < cutr * cutr * 0.9999f);
    unsigned long long mmask = __ballot(miss);
    while (mmask) {                    // inline fixup (normally skipped)
        int ml = __ffsll(mmask) - 1;
        mmask &= mmask - 1;
        int msq = blockIdx.x * 64 + ml;
        int mb = msq >> 13;
        float4 mq = squery[msq];
        float fv2[KNN]; int fi2[KNN];
#pragma unroll
        for (int r = 0; r < KNN; ++r) { fv2[r] = 3.4e38f; fi2[r] = 0; }
        for (int t = ql; t < N; t += 64) {
            float4 p = spts[(size_t)mb * N + t];
            float dx = p.x - mq.x, dy = p.y - mq.y, dz = p.z - mq.z;
            float dv = fmaf(dx, dx, fmaf(dy, dy, dz * dz));
            if (dv < fv2[KNN - 1]) CHAIN_INS(fv2, fi2, dv, t);
        }
#pragma unroll
        for (int rd = 0; rd < 6; ++rd) {   // bitonic tournament
            int dl = 1 << rd;
            float nv[KNN]; int nid[KNN];
#pragma unroll
            for (int i2 = 0; i2 < KNN; ++i2) {
                float pv = __shfl_xor(fv2[KNN - 1 - i2], dl, 64);
                int   pi = __shfl_xor(fi2[KNN - 1 - i2], dl, 64);
                bool take = fv2[i2] <= pv;
                nv[i2]  = take ? fv2[i2] : pv;
                nid[i2] = take ? fi2[i2] : pi;
            }
#pragma unroll
            for (int st = 8; st; st >>= 1) {
#pragma unroll
                for (int i2 = 0; i2 < KNN; ++i2) {
                    if (!(i2 & st)) {
                        int j2 = i2 | st;
                        bool sw = nv[i2] > nv[j2];
                        float ta = sw ? nv[j2] : nv[i2];
                        float tb = sw ? nv[i2] : nv[j2];
                        int ia = sw ? nid[j2] : nid[i2];
                        int ib = sw ? nid[i2] : nid[j2];
                        nv[i2] = ta; nv[j2] = tb; nid[i2] = ia; nid[j2] = ib;
                    }
                }
            }
#pragma unroll
            for (int i2 = 0; i2 < KNN; ++i2) { fv2[i2] = nv[i2]; fi2[i2] = nid[i2]; }
        }
        if (ql == ml) {
#pragma unroll
            for (int r = 0; r < KNN; ++r) { v[r] = fv2[r]; id[r] = fi2[r]; }
        }
    }
    int gq = __float_as_int(q4.w);
    w_out[gq] = (v[0] > 0.03f) ? 10.0f : 1.0f;
#pragma unroll
    for (int r = 0; r < KNN; ++r)                       // coalesced over ql
        idx_out[(size_t)r * BM + sqid] = sidx[b * N + id[r]];
}

// Kernel: MFMA gather+MLP+reduce. Wave per sorted query.
//   h (lane=d layout, 3 FMA + relu) -> bf16 transpose via padded LDS
//   (16 ds_write_b16 + 2 ds_read_b128) -> A-frags; W2 B-frags preloaded in
//   VGPRs (uniform); y = h @ W2 via 8x mfma_f32_16x16x32_bf16; C-layout
//   (row=(lane>>4)*4+i = k, col=lane&15 -> c) feeds gf-gather + shfl reduce.
__global__ __launch_bounds__(256) void k_final(const float4* __restrict__ squery,
                                               const int* __restrict__ idxs,
                                               const float* __restrict__ xyz1,
                                               const float* __restrict__ f,
                                               const float* __restrict__ W1,
                                               const float* __restrict__ b1,
                                               const float* __restrict__ W2,
                                               const float* __restrict__ b2,
                                               float* __restrict__ out) {
    __shared__ __align__(16) unsigned short hT[4][16][72];  // 9 KB, padded bf16
    int tid = threadIdx.x;
    int l   = tid & 63;
    int wv  = tid >> 6;
    int ln  = l & 15, lg = l >> 4;
    int mq  = blockIdx.x * 4 + wv;              // sorted query id
    int bb  = mq >> 13;
    float4 q4 = squery[mq];
    int gq = __float_as_int(q4.w);
    float qx = q4.x, qy = q4.y, qz = q4.z;

    // B-frags: B[k=(lg*8+j)+32s][n=ln] = W2[d][t*16+ln]; uniform, L1-hot.
    frag_ab bfrag[4][2];
#pragma unroll
    for (int t = 0; t < 4; ++t)
#pragma unroll
        for (int s = 0; s < 2; ++s) {
            frag_ab bv;
#pragma unroll
            for (int j = 0; j < 8; ++j)
                bv[j] = f2bf(W2[(lg * 8 + j + 32 * s) * 64 + t * 16 + ln]);
            bfrag[t][s] = bv;
        }

    float w10 = W1[l], w11 = W1[64 + l], w12 = W1[128 + l], b1c = b1[l];

    // h in lane=d layout; bf16 transpose into hT[k][d] (d = lane).
#pragma unroll
    for (int k = 0; k < KNN; ++k) {
        int nk = idxs[(size_t)k * BM + mq];               // wave-uniform
        const float* p = xyz1 + ((size_t)bb * N + nk) * 3;
        float gx = p[0] - qx, gy = p[1] - qy, gz = p[2] - qz;
        float t = fmaf(gx, w10, b1c);
        t = fmaf(gy, w11, t);
        t = fmaf(gz, w12, t);
        hT[wv][k][l] = (unsigned short)f2bf(fmaxf(t, 0.f));
    }
    // same-wave LDS RAW: compiler inserts lgkmcnt wait.

    frag_cd acc[4];
#pragma unroll
    for (int t = 0; t < 4; ++t) acc[t] = (frag_cd){0.f, 0.f, 0.f, 0.f};
#pragma unroll
    for (int s = 0; s < 2; ++s) {
        frag_ab af = *(const frag_ab*)&hT[wv][ln][lg * 8 + 32 * s];
#pragma unroll
        for (int t = 0; t < 4; ++t)
            acc[t] = __builtin_amdgcn_mfma_f32_16x16x32_bf16(af, bfrag[t][s],
                                                             acc[t], 0, 0, 0);
    }

    // gf rows for this lane's 4 k values (k = lg*4 + i)
    int nk4[4];
#pragma unroll
    for (int i = 0; i < 4; ++i)
        nk4[i] = idxs[(size_t)(lg * 4 + i) * BM + mq];

#pragma unroll
    for (int t = 0; t < 4; ++t) {
        float b2c = b2[t * 16 + ln];
        float s = 0.f;
#pragma unroll
        for (int i = 0; i < 4; ++i) {
            float gf = f[((size_t)bb * N + nk4[i]) * 64 + t * 16 + ln];
            s = fmaf(acc[t][i] + b2c, gf, s);
        }
        s += __shfl_xor(s, 16, 64);
        s += __shfl_xor(s, 32, 64);
        if (lg == t)
            out[(size_t)gq * 64 + t * 16 + ln] = s * 0.25f;   // 1/sqrt(16)
    }
}

extern "C" void kernel_launch(void* const* d_in, const int* in_sizes, int n_in,
                              void* d_out, int out_size, void* d_ws, size_t ws_size,
                              hipStream_t stream) {
    const float* feature1 = (const float*)d_in[0];
    const float* xyz1     = (const float*)d_in[1];
    const float* xyz2     = (const float*)d_in[2];
    const float* Wp       = (const float*)d_in[3];
    const float* bp       = (const float*)d_in[4];
    const float* W1       = (const float*)d_in[5];
    const float* b1       = (const float*)d_in[6];
    const float* W2       = (const float*)d_in[7];
    const float* b2       = (const float*)d_in[8];
    float* out = (float*)d_out;

    char* w = (char*)d_ws;
    float4*   spts   = (float4*)w;    w += (size_t)B * N * 16;
    float4*   squery = (float4*)w;    w += (size_t)B * M * 16;
    float*    f      = (float*)w;     w += (size_t)B * N * D * 4;
    int*      sidx   = (int*)w;       w += (size_t)B * N * 4;
    unsigned* pcount = (unsigned*)w;  w += (size_t)B * NC * 4;
    unsigned* qcount = (unsigned*)w;  w += (size_t)B * NSC * 4;
    unsigned* pstart = (unsigned*)w;  w += (size_t)B * NC * 4;
    unsigned* pcur   = (unsigned*)w;  w += (size_t)B * NC * 4;
    unsigned* qcur   = (unsigned*)w;  w += (size_t)B * NSC * 4;
    int*      wtab   = (int*)w;       w += (size_t)B * WTMAX * 4;
    int*      ntab   = (int*)w;       w += 16;
    float*    partd  = (float*)w;     w += (size_t)NSL * KNN * BM * 4;
    int*      parti  = (int*)w;       w += (size_t)NSL * KNN * BM * 4;
    int*      idxf   = (int*)w;       w += (size_t)KNN * BM * 4;
    float*    w_out  = out + (size_t)BM * D;

    // zero pcount + qcount (contiguous)
    hipMemsetAsync(pcount, 0, (size_t)(B * NC + B * NSC) * 4, stream);

    k_prep<<<B * N / 32, 256, 0, stream>>>(feature1, Wp, bp, xyz1, xyz2,
                                           pcount, qcount, f);
    k_scan<<<4, 256, 0, stream>>>(pcount, qcount, pstart, pcur, qcur, wtab, ntab);
    k_scatter<<<BM / 256, 256, 0, stream>>>(xyz1, xyz2, pcur, qcur, spts, sidx, squery);
    k_knn<<<B * WTMAX * 2, 256, 0, stream>>>(spts, squery, pstart, pcount,
                                             wtab, ntab, partd, parti);
    k_merge<<<BM / 64, 256, 0, stream>>>(squery, partd, parti, sidx, spts,
                                         idxf, w_out);
    k_final<<<BM / 4, 256, 0, stream>>>(squery, idxf, xyz1, f,
                                        W1, b1, W2, b2, out);
}